// Round 2
// baseline (258.341 us; speedup 1.0000x reference)
//
#include <hip/hip_runtime.h>

// FinDiffNonUniform: out[n,b] = sum_{s<7} coef[n,s] * y[n + off[n,s], b]
// N=8192, B=4096, S=7, fp32.
//
// Round-4: streaming register-rotating stencil. Previous versions were
// one-shot blocks (load burst -> wait -> consume -> exit): every wave paid a
// full load-latency round trip, load pipe drained at each block boundary ->
// 3.7 TB/s. Now each block owns a 32-row span of one 1024-float column chunk
// and slides a 10-row register window (STEP=4 rows/iter, fully unrolled ->
// all static indices, shifts become SSA renames). Prefetch for iter k+1 is
// issued BEFORE compute of iter k behind a compile-time memory barrier, so
// 4-8 row loads stay in flight for the whole block lifetime.
// Read amplification 38/32 = 1.19x. Grid = 1024 blocks = 4/CU: whole grid
// co-resident. Edge spans (2/256) take a generic offset-gather path so the
// hot pipeline has no clamps.

#define FD_N   8192
#define FD_B   4096
#define FD_S   7
#define HALO   3
#define STEP   4
#define WIN    (STEP + 2 * HALO)    // 10-row register window
#define SPAN   32                   // rows per block
#define NITER  (SPAN / STEP)        // 8
#define NSPAN  (FD_N / SPAN)        // 256
#define NCHUNK 4                    // 1024-float column chunks
#define NWG    (NSPAN * NCHUNK)     // 1024 blocks (divisible by 8)
#define NXCD   8

typedef float v4f __attribute__((ext_vector_type(4)));

__global__ __launch_bounds__(256) void
_FinDiffNonUniform_51608327029442_kernel(const float* __restrict__ y,
                                         const float* __restrict__ coef,
                                         const int*   __restrict__ offs,
                                         float*       __restrict__ out) {
    // Bijective XCD swizzle (NWG % 8 == 0): each XCD gets a contiguous run of
    // logical ids -> adjacent spans (which share 6 halo rows) co-reside in
    // the same per-XCD L2.
    const int bid   = blockIdx.x;
    const int id    = (bid & (NXCD - 1)) * (NWG / NXCD) + (bid >> 3);
    const int span  = id & (NSPAN - 1);
    const int chunk = id >> 8;                      // id / NSPAN
    const int n0    = span * SPAN;
    const int b     = (chunk << 10) + (threadIdx.x << 2);

    if (span == 0 || span == NSPAN - 1) {
        // ---- edge spans: generic gather with real (one-sided) offsets ----
#pragma unroll 4
        for (int r = 0; r < SPAN; ++r) {
            const int n = n0 + r;
            v4f acc = (v4f){0.f, 0.f, 0.f, 0.f};
#pragma unroll
            for (int s = 0; s < FD_S; ++s) {
                const float cc = coef[(size_t)n * FD_S + s];   // block-uniform
                const int   o  = offs[(size_t)n * FD_S + s];
                const v4f   v  =
                    *reinterpret_cast<const v4f*>(y + (size_t)(n + o) * FD_B + b);
                acc += cc * v;
            }
            __builtin_nontemporal_store(
                acc, reinterpret_cast<v4f*>(out + (size_t)n * FD_B + b));
        }
        return;
    }

    // ---- interior spans: register-rotating centered stencil ----
    // Window rows are n0-3 .. n0+SPAN+2; interior spans never go OOB.
    const float* ybase = y   + (size_t)(n0 - HALO) * FD_B + b;
    float*       obase = out + (size_t)n0          * FD_B + b;

    v4f w[WIN];                       // w[j] = row (n0 - 3 + a + j) at iter a
#pragma unroll
    for (int j = 0; j < WIN; ++j)
        w[j] = *reinterpret_cast<const v4f*>(ybase + (size_t)j * FD_B);
    asm volatile("" ::: "memory");    // loads may not sink below this point

#pragma unroll
    for (int k = 0; k < NITER; ++k) {
        const int a = k * STEP;       // row offset within span (compile-time)

        // Prefetch the next STEP rows before consuming the current window.
        v4f p[STEP];
        if (k + 1 < NITER) {
#pragma unroll
            for (int j = 0; j < STEP; ++j)
                p[j] = *reinterpret_cast<const v4f*>(
                           ybase + (size_t)(a + WIN + j) * FD_B);
            asm volatile("" ::: "memory");
        }

        // Block-uniform coefficients -> scalar loads.
        float c[STEP][FD_S];
#pragma unroll
        for (int r = 0; r < STEP; ++r)
#pragma unroll
            for (int s = 0; s < FD_S; ++s)
                c[r][s] = coef[(size_t)(n0 + a + r) * FD_S + s];

        // Compute + store one row at a time (acc stays at 4 VGPRs).
#pragma unroll
        for (int r = 0; r < STEP; ++r) {
            v4f acc = c[r][0] * w[r];
#pragma unroll
            for (int s = 1; s < FD_S; ++s)
                acc += c[r][s] * w[r + s];
            __builtin_nontemporal_store(
                acc, reinterpret_cast<v4f*>(obase + (size_t)(a + r) * FD_B));
        }

        // Slide the window: pure register renaming after full unroll.
        if (k + 1 < NITER) {
#pragma unroll
            for (int j = 0; j < WIN - STEP; ++j) w[j] = w[j + STEP];
#pragma unroll
            for (int j = 0; j < STEP; ++j)       w[WIN - STEP + j] = p[j];
        }
    }
}

extern "C" void kernel_launch(void* const* d_in, const int* in_sizes, int n_in,
                              void* d_out, int out_size, void* d_ws, size_t ws_size,
                              hipStream_t stream) {
    const float* y    = (const float*)d_in[0];
    const float* coef = (const float*)d_in[1];
    const int*   offs = (const int*)d_in[2];
    float*       out  = (float*)d_out;

    _FinDiffNonUniform_51608327029442_kernel<<<NWG, 256, 0, stream>>>(y, coef, offs, out);
}